// Round 1
// baseline (823.116 us; speedup 1.0000x reference)
//
#include <hip/hip_runtime.h>
#include <cstdint>

// ===================== GCN encoder on MI355X =====================
// out = gcn(relu(gcn(x, W1, b1)), W2, b2)
// gcn(x,W,b)[i] = dinv[i] * ( sum_{e: dst=i} (xW*dinv)[src] + (xW*dinv)[i] ) + b
// where dinv = rsqrt(indeg+1) (self-loop included), same for both layers.
//
// Pipeline per call:
//  1. count in-degrees (int atomics)         -> degcnt
//  2. dinv[i] = rsqrt(degcnt[i]+1)
//  3. exclusive scan of degcnt               -> rowptr (3-kernel scan)
//  4. fill CSR src lists (int atomics on cursor)
//  5. gemm1: bufA = (x @ W1) * dinv[row]
//  6. aggregate+bias+relu (pull, no atomics) -> bufB
//  7. gemm2: bufA = (bufB @ W2) * dinv[row]
//  8. aggregate+bias                         -> d_out

// ---------------- graph build ----------------

__global__ void count_kernel(const int* __restrict__ dst, int* __restrict__ degcnt, int E) {
    int e = blockIdx.x * blockDim.x + threadIdx.x;
    if (e < E) atomicAdd(&degcnt[dst[e]], 1);
}

__global__ void dinv_kernel(const int* __restrict__ degcnt, float* __restrict__ dinv, int N) {
    int i = blockIdx.x * blockDim.x + threadIdx.x;
    if (i < N) dinv[i] = rsqrtf((float)(degcnt[i] + 1));
}

// chunk = 1024 elements per block (256 threads x 4). Writes exclusive-scan-
// within-chunk into part[] and chunk total into blocksums[chunk].
__global__ void scan1_kernel(const int* __restrict__ degcnt, int* __restrict__ part,
                             int* __restrict__ blocksums, int N) {
    __shared__ int ts[256];
    int t = threadIdx.x;
    int base = blockIdx.x * 1024 + t * 4;
    int v0 = (base + 0 < N) ? degcnt[base + 0] : 0;
    int v1 = (base + 1 < N) ? degcnt[base + 1] : 0;
    int v2 = (base + 2 < N) ? degcnt[base + 2] : 0;
    int v3 = (base + 3 < N) ? degcnt[base + 3] : 0;
    int tsum = v0 + v1 + v2 + v3;
    ts[t] = tsum;
    __syncthreads();
    for (int ofs = 1; ofs < 256; ofs <<= 1) {
        int val = (t >= ofs) ? ts[t - ofs] : 0;
        __syncthreads();
        ts[t] += val;
        __syncthreads();
    }
    int excl = ts[t] - tsum;
    if (base + 0 < N) part[base + 0] = excl;
    if (base + 1 < N) part[base + 1] = excl + v0;
    if (base + 2 < N) part[base + 2] = excl + v0 + v1;
    if (base + 3 < N) part[base + 3] = excl + v0 + v1 + v2;
    if (t == 255) blocksums[blockIdx.x] = ts[255];
}

// single block: exclusive scan of blocksums[0..n), n <= 256
__global__ void scan2_kernel(int* __restrict__ blocksums, int n) {
    __shared__ int ts[256];
    int t = threadIdx.x;
    int v = (t < n) ? blocksums[t] : 0;
    ts[t] = v;
    __syncthreads();
    for (int ofs = 1; ofs < 256; ofs <<= 1) {
        int val = (t >= ofs) ? ts[t - ofs] : 0;
        __syncthreads();
        ts[t] += val;
        __syncthreads();
    }
    if (t < n) blocksums[t] = ts[t] - v;  // exclusive
}

__global__ void scan3_kernel(int* __restrict__ rowptr, const int* __restrict__ blocksums,
                             int* __restrict__ cursor, int N, int E) {
    int i = blockIdx.x * blockDim.x + threadIdx.x;
    if (i < N) {
        int r = rowptr[i] + blocksums[i >> 10];
        rowptr[i] = r;
        cursor[i] = r;
    }
    if (i == 0) rowptr[N] = E;
}

__global__ void fill_kernel(const int* __restrict__ src, const int* __restrict__ dst,
                            int* __restrict__ cursor, int* __restrict__ csr, int E) {
    int e = blockIdx.x * blockDim.x + threadIdx.x;
    if (e < E) {
        int d = dst[e];
        int p = atomicAdd(&cursor[d], 1);
        csr[p] = src[e];
    }
}

// ---------------- GEMM: Y[M,64] = (X[M,K] @ W[K,64]) * dinv[row] ----------------
// 64 rows/block, 256 threads, each thread computes a 4x4 tile.
// Xs padded +4 floats/row to break 4-way LDS bank aliasing on the x reads.

template <int K>
__global__ __launch_bounds__(256) void gemm_scaled(const float* __restrict__ X,
                                                   const float* __restrict__ W,
                                                   const float* __restrict__ dinv,
                                                   float* __restrict__ Y, int M) {
    __shared__ float Ws[K * 64];
    __shared__ float Xs[64 * (K + 4)];
    int t = threadIdx.x;

    for (int i = t; i < K * 64 / 4; i += 256)
        ((float4*)Ws)[i] = ((const float4*)W)[i];

    int row0 = blockIdx.x * 64;
    for (int i = t; i < 64 * K / 4; i += 256) {
        int idx = i * 4;
        int r = idx / K;
        int c = idx - r * K;
        float4 v = make_float4(0.f, 0.f, 0.f, 0.f);
        int gr = row0 + r;
        if (gr < M) v = *(const float4*)(X + (size_t)gr * K + c);
        *(float4*)(&Xs[r * (K + 4) + c]) = v;
    }
    __syncthreads();

    int cg = (t & 15) * 4;   // output cols cg..cg+3
    int rg = (t >> 4) * 4;   // output rows rg..rg+3 (within tile)

    float acc[4][4];
#pragma unroll
    for (int j = 0; j < 4; j++)
#pragma unroll
        for (int c = 0; c < 4; c++) acc[j][c] = 0.f;

#pragma unroll 4
    for (int k = 0; k < K; k++) {
        float4 w = *(float4*)(&Ws[k * 64 + cg]);
#pragma unroll
        for (int j = 0; j < 4; j++) {
            float xv = Xs[(rg + j) * (K + 4) + k];
            acc[j][0] = fmaf(xv, w.x, acc[j][0]);
            acc[j][1] = fmaf(xv, w.y, acc[j][1]);
            acc[j][2] = fmaf(xv, w.z, acc[j][2]);
            acc[j][3] = fmaf(xv, w.w, acc[j][3]);
        }
    }

#pragma unroll
    for (int j = 0; j < 4; j++) {
        int r = row0 + rg + j;
        if (r < M) {
            float d = dinv[r];
            float4 o = make_float4(acc[j][0] * d, acc[j][1] * d, acc[j][2] * d, acc[j][3] * d);
            *(float4*)(Y + (size_t)r * 64 + cg) = o;
        }
    }
}

// ---------------- pull aggregation + epilogue ----------------
// 16 lanes per node, one float4 (4 features) per lane; register accumulate.
// out[i] = [relu]( dinv[i] * (sum_{e in CSR row i} hs[src] + hs[i]) + bias )

__global__ __launch_bounds__(256) void aggregate_kernel(const float* __restrict__ hs,
                                                        const int* __restrict__ rowptr,
                                                        const int* __restrict__ csr,
                                                        const float* __restrict__ dinv,
                                                        const float* __restrict__ bias,
                                                        float* __restrict__ out, int N,
                                                        int do_relu) {
    int t = threadIdx.x;
    int node = blockIdx.x * 16 + (t >> 4);
    if (node >= N) return;
    int sub = t & 15;

    float4 acc = *(const float4*)(hs + (size_t)node * 64 + sub * 4);  // self-loop term
    int e0 = rowptr[node];
    int e1 = rowptr[node + 1];
    for (int e = e0; e < e1; ++e) {
        int s = csr[e];
        float4 v = *(const float4*)(hs + (size_t)s * 64 + sub * 4);
        acc.x += v.x;
        acc.y += v.y;
        acc.z += v.z;
        acc.w += v.w;
    }
    float d = dinv[node];
    float4 b = *(const float4*)(bias + sub * 4);
    float4 o = make_float4(fmaf(acc.x, d, b.x), fmaf(acc.y, d, b.y),
                           fmaf(acc.z, d, b.z), fmaf(acc.w, d, b.w));
    if (do_relu) {
        o.x = fmaxf(o.x, 0.f);
        o.y = fmaxf(o.y, 0.f);
        o.z = fmaxf(o.z, 0.f);
        o.w = fmaxf(o.w, 0.f);
    }
    *(float4*)(out + (size_t)node * 64 + sub * 4) = o;
}

// ---------------- launch ----------------

extern "C" void kernel_launch(void* const* d_in, const int* in_sizes, int n_in,
                              void* d_out, int out_size, void* d_ws, size_t ws_size,
                              hipStream_t stream) {
    const float* x  = (const float*)d_in[0];
    const int*   ei = (const int*)d_in[1];   // int32 per harness convention, [2, E]
    const float* W1 = (const float*)d_in[2];
    const float* b1 = (const float*)d_in[3];
    const float* W2 = (const float*)d_in[4];
    const float* b2 = (const float*)d_in[5];

    const int N = in_sizes[0] / 128;  // 100000
    const int E = in_sizes[1] / 2;    // 3200000
    const int* src = ei;
    const int* dst = ei + E;
    float* out = (float*)d_out;

    char* ws = (char*)d_ws;
    size_t off = 0;
    auto alloc = [&](size_t bytes) -> char* {
        char* p = ws + off;
        off = (off + bytes + 255) & ~(size_t)255;
        return p;
    };
    int*   degcnt    = (int*)alloc((size_t)N * 4);
    float* dinv      = (float*)alloc((size_t)N * 4);
    int*   rowptr    = (int*)alloc((size_t)(N + 1) * 4);
    int*   cursor    = (int*)alloc((size_t)N * 4);
    int*   blocksums = (int*)alloc(256 * 4);
    int*   csr       = (int*)alloc((size_t)E * 4);
    float* bufA      = (float*)alloc((size_t)N * 64 * 4);  // h*dinv (layer1), then h2*dinv
    float* bufB      = (float*)alloc((size_t)N * 64 * 4);  // relu'd layer-1 output

    hipMemsetAsync(degcnt, 0, (size_t)N * 4, stream);

    int nchunks = (N + 1023) / 1024;  // 98
    count_kernel<<<(E + 255) / 256, 256, 0, stream>>>(dst, degcnt, E);
    dinv_kernel<<<(N + 255) / 256, 256, 0, stream>>>(degcnt, dinv, N);
    scan1_kernel<<<nchunks, 256, 0, stream>>>(degcnt, rowptr, blocksums, N);
    scan2_kernel<<<1, 256, 0, stream>>>(blocksums, nchunks);
    scan3_kernel<<<(N + 255) / 256, 256, 0, stream>>>(rowptr, blocksums, cursor, N, E);
    fill_kernel<<<(E + 255) / 256, 256, 0, stream>>>(src, dst, cursor, csr, E);

    gemm_scaled<128><<<(N + 63) / 64, 256, 0, stream>>>(x, W1, dinv, bufA, N);
    aggregate_kernel<<<(N + 15) / 16, 256, 0, stream>>>(bufA, rowptr, csr, dinv, b1, bufB, N, 1);
    gemm_scaled<64><<<(N + 63) / 64, 256, 0, stream>>>(bufB, W2, dinv, bufA, N);
    aggregate_kernel<<<(N + 15) / 16, 256, 0, stream>>>(bufA, rowptr, csr, dinv, b2, out, N, 0);
}

// Round 2
// 609.188 us; speedup vs baseline: 1.3512x; 1.3512x over previous
//
#include <hip/hip_runtime.h>
#include <cstdint>

// ===================== GCN encoder on MI355X =====================
// out = gcn(relu(gcn(x, W1, b1)), W2, b2)
// gcn(x,W,b)[i] = dinv[i] * ( sum_{e: dst=i} (xW*dinv)[src] + (xW*dinv)[i] ) + b
// dinv = rsqrt(indeg+1) (self-loop), identical for both layers.
//
// Graph build (per call, workspace re-poisoned every launch):
//  1. countpos: posr[e] = atomicAdd(degcnt[dst[e]], 1)   (count + claim position)
//  2. dinv[i] = rsqrt(degcnt[i]+1)
//  3. exclusive scan of degcnt -> rowptr
//  4. scatter: csr[rowptr[dst[e]] + posr[e]] = src[e]    (NO atomics, no dependency)
// Then gemm1 -> aggregate(relu) -> gemm2 -> aggregate -> out.

// ---------------- graph build ----------------

// Fused degree count + position claim. 4 edges/thread via grid-stride so the
// returning atomics pipeline (independent chains).
__global__ void countpos_kernel(const int* __restrict__ dst, int* __restrict__ degcnt,
                                int* __restrict__ posr, int E) {
    int i = blockIdx.x * blockDim.x + threadIdx.x;
    int stride = gridDim.x * blockDim.x;
    for (int e = i; e < E; e += stride)
        posr[e] = atomicAdd(&degcnt[dst[e]], 1);
}

__global__ void dinv_kernel(const int* __restrict__ degcnt, float* __restrict__ dinv, int N) {
    int i = blockIdx.x * blockDim.x + threadIdx.x;
    if (i < N) dinv[i] = rsqrtf((float)(degcnt[i] + 1));
}

// chunk = 1024 elements per block (256 threads x 4). Exclusive scan within
// chunk into part[], chunk total into blocksums[chunk].
__global__ void scan1_kernel(const int* __restrict__ degcnt, int* __restrict__ part,
                             int* __restrict__ blocksums, int N) {
    __shared__ int ts[256];
    int t = threadIdx.x;
    int base = blockIdx.x * 1024 + t * 4;
    int v0 = (base + 0 < N) ? degcnt[base + 0] : 0;
    int v1 = (base + 1 < N) ? degcnt[base + 1] : 0;
    int v2 = (base + 2 < N) ? degcnt[base + 2] : 0;
    int v3 = (base + 3 < N) ? degcnt[base + 3] : 0;
    int tsum = v0 + v1 + v2 + v3;
    ts[t] = tsum;
    __syncthreads();
    for (int ofs = 1; ofs < 256; ofs <<= 1) {
        int val = (t >= ofs) ? ts[t - ofs] : 0;
        __syncthreads();
        ts[t] += val;
        __syncthreads();
    }
    int excl = ts[t] - tsum;
    if (base + 0 < N) part[base + 0] = excl;
    if (base + 1 < N) part[base + 1] = excl + v0;
    if (base + 2 < N) part[base + 2] = excl + v0 + v1;
    if (base + 3 < N) part[base + 3] = excl + v0 + v1 + v2;
    if (t == 255) blocksums[blockIdx.x] = ts[255];
}

// single block: exclusive scan of blocksums[0..n), n <= 256
__global__ void scan2_kernel(int* __restrict__ blocksums, int n) {
    __shared__ int ts[256];
    int t = threadIdx.x;
    int v = (t < n) ? blocksums[t] : 0;
    ts[t] = v;
    __syncthreads();
    for (int ofs = 1; ofs < 256; ofs <<= 1) {
        int val = (t >= ofs) ? ts[t - ofs] : 0;
        __syncthreads();
        ts[t] += val;
        __syncthreads();
    }
    if (t < n) blocksums[t] = ts[t] - v;  // exclusive
}

__global__ void scan3_kernel(int* __restrict__ rowptr, const int* __restrict__ blocksums,
                             int N, int E) {
    int i = blockIdx.x * blockDim.x + threadIdx.x;
    if (i < N) rowptr[i] = rowptr[i] + blocksums[i >> 10];
    if (i == 0) rowptr[N] = E;
}

// Dependency-free scatter: position fully precomputed, stores pipeline freely.
__global__ void scatter_kernel(const int* __restrict__ src, const int* __restrict__ dst,
                               const int* __restrict__ posr, const int* __restrict__ rowptr,
                               int* __restrict__ csr, int E) {
    int i = blockIdx.x * blockDim.x + threadIdx.x;
    int stride = gridDim.x * blockDim.x;
    for (int e = i; e < E; e += stride)
        csr[rowptr[dst[e]] + posr[e]] = src[e];
}

// ---------------- GEMM: Y[M,64] = (X[M,K] @ W[K,64]) * dinv[row] ----------------

template <int K>
__global__ __launch_bounds__(256) void gemm_scaled(const float* __restrict__ X,
                                                   const float* __restrict__ W,
                                                   const float* __restrict__ dinv,
                                                   float* __restrict__ Y, int M) {
    __shared__ float Ws[K * 64];
    __shared__ float Xs[64 * (K + 4)];
    int t = threadIdx.x;

    for (int i = t; i < K * 64 / 4; i += 256)
        ((float4*)Ws)[i] = ((const float4*)W)[i];

    int row0 = blockIdx.x * 64;
    for (int i = t; i < 64 * K / 4; i += 256) {
        int idx = i * 4;
        int r = idx / K;
        int c = idx - r * K;
        float4 v = make_float4(0.f, 0.f, 0.f, 0.f);
        int gr = row0 + r;
        if (gr < M) v = *(const float4*)(X + (size_t)gr * K + c);
        *(float4*)(&Xs[r * (K + 4) + c]) = v;
    }
    __syncthreads();

    int cg = (t & 15) * 4;   // output cols cg..cg+3
    int rg = (t >> 4) * 4;   // output rows rg..rg+3 (within tile)

    float acc[4][4];
#pragma unroll
    for (int j = 0; j < 4; j++)
#pragma unroll
        for (int c = 0; c < 4; c++) acc[j][c] = 0.f;

#pragma unroll 4
    for (int k = 0; k < K; k++) {
        float4 w = *(float4*)(&Ws[k * 64 + cg]);
#pragma unroll
        for (int j = 0; j < 4; j++) {
            float xv = Xs[(rg + j) * (K + 4) + k];
            acc[j][0] = fmaf(xv, w.x, acc[j][0]);
            acc[j][1] = fmaf(xv, w.y, acc[j][1]);
            acc[j][2] = fmaf(xv, w.z, acc[j][2]);
            acc[j][3] = fmaf(xv, w.w, acc[j][3]);
        }
    }

#pragma unroll
    for (int j = 0; j < 4; j++) {
        int r = row0 + rg + j;
        if (r < M) {
            float d = dinv[r];
            float4 o = make_float4(acc[j][0] * d, acc[j][1] * d, acc[j][2] * d, acc[j][3] * d);
            *(float4*)(Y + (size_t)r * 64 + cg) = o;
        }
    }
}

// ---------------- pull aggregation + epilogue ----------------
// 16 lanes per node, one float4 per lane. CSR indices are fetched 16-at-a-time
// by the group (one lane-parallel load), broadcast via shfl, so 16 row-gathers
// are in flight per inner loop — memory-level parallelism instead of a
// serialized csr->gather chain per edge.

__global__ __launch_bounds__(256) void aggregate_kernel(const float* __restrict__ hs,
                                                        const int* __restrict__ rowptr,
                                                        const int* __restrict__ csr,
                                                        const float* __restrict__ dinv,
                                                        const float* __restrict__ bias,
                                                        float* __restrict__ out, int N,
                                                        int do_relu) {
    int t = threadIdx.x;
    int node = blockIdx.x * 16 + (t >> 4);
    if (node >= N) return;
    int sub = t & 15;
    int gbase = t & 0x30;  // group base lane within the wave

    float4 acc = *(const float4*)(hs + (size_t)node * 64 + sub * 4);  // self-loop
    int e0 = rowptr[node];
    int e1 = rowptr[node + 1];

    int e = e0;
    for (; e + 16 <= e1; e += 16) {
        int idx = csr[e + sub];
#pragma unroll
        for (int j = 0; j < 16; ++j) {
            int s = __shfl(idx, gbase + j, 64);
            float4 v = *(const float4*)(hs + (size_t)s * 64 + sub * 4);
            acc.x += v.x;
            acc.y += v.y;
            acc.z += v.z;
            acc.w += v.w;
        }
    }
    for (; e < e1; ++e) {
        int s = csr[e];
        float4 v = *(const float4*)(hs + (size_t)s * 64 + sub * 4);
        acc.x += v.x;
        acc.y += v.y;
        acc.z += v.z;
        acc.w += v.w;
    }

    float d = dinv[node];
    float4 b = *(const float4*)(bias + sub * 4);
    float4 o = make_float4(fmaf(acc.x, d, b.x), fmaf(acc.y, d, b.y),
                           fmaf(acc.z, d, b.z), fmaf(acc.w, d, b.w));
    if (do_relu) {
        o.x = fmaxf(o.x, 0.f);
        o.y = fmaxf(o.y, 0.f);
        o.z = fmaxf(o.z, 0.f);
        o.w = fmaxf(o.w, 0.f);
    }
    *(float4*)(out + (size_t)node * 64 + sub * 4) = o;
}

// ---------------- launch ----------------

extern "C" void kernel_launch(void* const* d_in, const int* in_sizes, int n_in,
                              void* d_out, int out_size, void* d_ws, size_t ws_size,
                              hipStream_t stream) {
    const float* x  = (const float*)d_in[0];
    const int*   ei = (const int*)d_in[1];   // [2, E] int32
    const float* W1 = (const float*)d_in[2];
    const float* b1 = (const float*)d_in[3];
    const float* W2 = (const float*)d_in[4];
    const float* b2 = (const float*)d_in[5];

    const int N = in_sizes[0] / 128;  // 100000
    const int E = in_sizes[1] / 2;    // 3200000
    const int* src = ei;
    const int* dst = ei + E;
    float* out = (float*)d_out;

    char* ws = (char*)d_ws;
    size_t off = 0;
    auto alloc = [&](size_t bytes) -> char* {
        char* p = ws + off;
        off = (off + bytes + 255) & ~(size_t)255;
        return p;
    };
    int*   degcnt    = (int*)alloc((size_t)N * 4);
    float* dinv      = (float*)alloc((size_t)N * 4);
    int*   rowptr    = (int*)alloc((size_t)(N + 1) * 4);
    int*   blocksums = (int*)alloc(256 * 4);
    int*   posr      = (int*)alloc((size_t)E * 4);
    int*   csr       = (int*)alloc((size_t)E * 4);
    float* bufA      = (float*)alloc((size_t)N * 64 * 4);
    float* bufB      = (float*)alloc((size_t)N * 64 * 4);

    hipMemsetAsync(degcnt, 0, (size_t)N * 4, stream);

    int nchunks = (N + 1023) / 1024;  // 98
    // 4 edges per thread, grid-stride, so returning atomics pipeline.
    int cp_blocks = (E / 4 + 255) / 256;
    countpos_kernel<<<cp_blocks, 256, 0, stream>>>(dst, degcnt, posr, E);
    dinv_kernel<<<(N + 255) / 256, 256, 0, stream>>>(degcnt, dinv, N);
    scan1_kernel<<<nchunks, 256, 0, stream>>>(degcnt, rowptr, blocksums, N);
    scan2_kernel<<<1, 256, 0, stream>>>(blocksums, nchunks);
    scan3_kernel<<<(N + 255) / 256, 256, 0, stream>>>(rowptr, blocksums, N, E);
    scatter_kernel<<<cp_blocks, 256, 0, stream>>>(src, dst, posr, rowptr, csr, E);

    gemm_scaled<128><<<(N + 63) / 64, 256, 0, stream>>>(x, W1, dinv, bufA, N);
    aggregate_kernel<<<(N + 15) / 16, 256, 0, stream>>>(bufA, rowptr, csr, dinv, b1, bufB, N, 1);
    gemm_scaled<64><<<(N + 63) / 64, 256, 0, stream>>>(bufB, W2, dinv, bufA, N);
    aggregate_kernel<<<(N + 15) / 16, 256, 0, stream>>>(bufA, rowptr, csr, dinv, b2, out, N, 0);
}

// Round 3
// 475.729 us; speedup vs baseline: 1.7302x; 1.2805x over previous
//
#include <hip/hip_runtime.h>
#include <cstdint>

// ===================== GCN encoder on MI355X =====================
// out = gcn(relu(gcn(x, W1, b1)), W2, b2)
// gcn(x,W,b)[i] = dinv[i] * ( sum_{e: dst=i} (xW*dinv)[src] + (xW*dinv)[i] ) + b
// dinv = rsqrt(indeg+1) (self-loop), identical for both layers.
//
// Graph build with ZERO global atomics (R2's countpos was fabric-atomic bound,
// 24 G atomics/s, 131 us):
//  A. hist:      per-block LDS histogram over node-buckets (128 nodes/bucket),
//                coalesced write to histmat[block][bucket]
//  B. scancol:   per-bucket exclusive scan over blocks  -> colbase (in-place)
//     scanbucket: exclusive scan of bucket totals       -> bucketbase
//  C. bscatter:  re-read edges, LDS cursors claim slots, write packed
//                (dst_local<<17 | src) into bucket-contiguous regions
//  D. bcsr:      one block per bucket: LDS degree count + LDS scan ->
//                rowptr + dinv (fused) + coalesced csr write
// Then gemm1 -> aggregate(relu) -> gemm2 -> aggregate -> out.

#define BSHIFT 7          // 128 nodes per bucket
#define NBMAX 784         // >= ceil(100000/128) = 782
#define CH 8192           // edges per block in passes A/C

// ---------------- pass A: bucket histogram ----------------
__global__ __launch_bounds__(256) void hist_kernel(const int* __restrict__ dst,
                                                   int* __restrict__ histmat,
                                                   int E, int nb) {
    __shared__ int hist[NBMAX];
    int t = threadIdx.x;
    for (int b = t; b < nb; b += 256) hist[b] = 0;
    __syncthreads();
    int base = blockIdx.x * CH;
#pragma unroll
    for (int j = 0; j < CH / 1024; ++j) {
        int idx = base + j * 1024 + t * 4;
        if (idx + 4 <= E) {
            int4 d = *(const int4*)(dst + idx);
            atomicAdd(&hist[d.x >> BSHIFT], 1);
            atomicAdd(&hist[d.y >> BSHIFT], 1);
            atomicAdd(&hist[d.z >> BSHIFT], 1);
            atomicAdd(&hist[d.w >> BSHIFT], 1);
        } else {
            for (int k = 0; k < 4; ++k)
                if (idx + k < E) atomicAdd(&hist[dst[idx + k] >> BSHIFT], 1);
        }
    }
    __syncthreads();
    for (int b = t; b < nb; b += 256) histmat[blockIdx.x * nb + b] = hist[b];
}

// ---------------- pass B1: per-bucket scan over blocks (in-place ok) --------
__global__ __launch_bounds__(256) void scancol_kernel(const int* __restrict__ histmat,
                                                      int* __restrict__ colbase,
                                                      int* __restrict__ buckettotal,
                                                      int nb, int nblk) {
    __shared__ int ts[256];
    int b = blockIdx.x;
    int t = threadIdx.x;
    int v[4];
    int tsum = 0;
#pragma unroll
    for (int k = 0; k < 4; ++k) {
        int blk = t * 4 + k;
        v[k] = (blk < nblk) ? histmat[blk * nb + b] : 0;
        tsum += v[k];
    }
    ts[t] = tsum;
    __syncthreads();
    for (int ofs = 1; ofs < 256; ofs <<= 1) {
        int val = (t >= ofs) ? ts[t - ofs] : 0;
        __syncthreads();
        ts[t] += val;
        __syncthreads();
    }
    int run = ts[t] - tsum;
#pragma unroll
    for (int k = 0; k < 4; ++k) {
        int blk = t * 4 + k;
        if (blk < nblk) colbase[blk * nb + b] = run;
        run += v[k];
    }
    if (t == 255) buckettotal[b] = ts[255];
}

// ---------------- pass B2: scan bucket totals (single block) ----------------
__global__ __launch_bounds__(256) void scanbucket_kernel(const int* __restrict__ buckettotal,
                                                         int* __restrict__ bucketbase,
                                                         int nb, int E) {
    __shared__ int ts[256];
    int t = threadIdx.x;
    int v[4];
    int tsum = 0;
#pragma unroll
    for (int k = 0; k < 4; ++k) {
        int b = t * 4 + k;
        v[k] = (b < nb) ? buckettotal[b] : 0;
        tsum += v[k];
    }
    ts[t] = tsum;
    __syncthreads();
    for (int ofs = 1; ofs < 256; ofs <<= 1) {
        int val = (t >= ofs) ? ts[t - ofs] : 0;
        __syncthreads();
        ts[t] += val;
        __syncthreads();
    }
    int run = ts[t] - tsum;
#pragma unroll
    for (int k = 0; k < 4; ++k) {
        int b = t * 4 + k;
        if (b < nb) bucketbase[b] = run;
        run += v[k];
    }
    if (t == 0) bucketbase[nb] = E;
}

// ---------------- pass C: scatter into bucket regions (LDS cursors) ---------
__global__ __launch_bounds__(256) void bscatter_kernel(const int* __restrict__ src,
                                                       const int* __restrict__ dst,
                                                       const int* __restrict__ colbase,
                                                       const int* __restrict__ bucketbase,
                                                       int* __restrict__ packed,
                                                       int E, int nb) {
    __shared__ int cur[NBMAX];
    int t = threadIdx.x;
    for (int b = t; b < nb; b += 256)
        cur[b] = bucketbase[b] + colbase[blockIdx.x * nb + b];
    __syncthreads();
    int base = blockIdx.x * CH;
#pragma unroll
    for (int j = 0; j < CH / 1024; ++j) {
        int idx = base + j * 1024 + t * 4;
        if (idx + 4 <= E) {
            int4 d = *(const int4*)(dst + idx);
            int4 s = *(const int4*)(src + idx);
            int p;
            p = atomicAdd(&cur[d.x >> BSHIFT], 1); packed[p] = ((d.x & 127) << 17) | s.x;
            p = atomicAdd(&cur[d.y >> BSHIFT], 1); packed[p] = ((d.y & 127) << 17) | s.y;
            p = atomicAdd(&cur[d.z >> BSHIFT], 1); packed[p] = ((d.z & 127) << 17) | s.z;
            p = atomicAdd(&cur[d.w >> BSHIFT], 1); packed[p] = ((d.w & 127) << 17) | s.w;
        } else {
            for (int k = 0; k < 4; ++k)
                if (idx + k < E) {
                    int dd = dst[idx + k], ss = src[idx + k];
                    int p = atomicAdd(&cur[dd >> BSHIFT], 1);
                    packed[p] = ((dd & 127) << 17) | ss;
                }
        }
    }
}

// ---------------- pass D: within-bucket CSR + rowptr + dinv ----------------
__global__ __launch_bounds__(256) void bcsr_kernel(const int* __restrict__ packed,
                                                   const int* __restrict__ bucketbase,
                                                   int* __restrict__ rowptr,
                                                   float* __restrict__ dinv,
                                                   int* __restrict__ csr,
                                                   int N, int nb) {
    __shared__ int deg[128];
    __shared__ int lrp[128];
    __shared__ int ts[128];
    int b = blockIdx.x;
    int t = threadIdx.x;
    if (t < 128) deg[t] = 0;
    __syncthreads();
    int bb0 = bucketbase[b];
    int bb1 = bucketbase[b + 1];
    for (int i = bb0 + t; i < bb1; i += 256)
        atomicAdd(&deg[packed[i] >> 17], 1);
    __syncthreads();
    if (t < 128) ts[t] = deg[t];
    __syncthreads();
    for (int ofs = 1; ofs < 128; ofs <<= 1) {
        int v = (t < 128 && t >= ofs) ? ts[t - ofs] : 0;
        __syncthreads();
        if (t < 128) ts[t] += v;
        __syncthreads();
    }
    int node0 = b << BSHIFT;
    int nlocal = min(128, N - node0);
    if (t < 128) lrp[t] = ts[t] - deg[t];  // exclusive; doubles as cursor below
    if (t < nlocal) {
        rowptr[node0 + t] = bb0 + (ts[t] - deg[t]);
        dinv[node0 + t] = rsqrtf((float)(deg[t] + 1));
    }
    if (t == nlocal) rowptr[node0 + nlocal] = bb1;
    __syncthreads();
    for (int i = bb0 + t; i < bb1; i += 256) {
        int v = packed[i];
        int p = atomicAdd(&lrp[v >> 17], 1);
        csr[bb0 + p] = v & 0x1FFFF;
    }
}

// ---------------- GEMM: Y[M,64] = (X[M,K] @ W[K,64]) * dinv[row] ------------
template <int K>
__global__ __launch_bounds__(256) void gemm_scaled(const float* __restrict__ X,
                                                   const float* __restrict__ W,
                                                   const float* __restrict__ dinv,
                                                   float* __restrict__ Y, int M) {
    __shared__ float Ws[K * 64];
    __shared__ float Xs[64 * (K + 4)];
    int t = threadIdx.x;

    for (int i = t; i < K * 64 / 4; i += 256)
        ((float4*)Ws)[i] = ((const float4*)W)[i];

    int row0 = blockIdx.x * 64;
    for (int i = t; i < 64 * K / 4; i += 256) {
        int idx = i * 4;
        int r = idx / K;
        int c = idx - r * K;
        float4 v = make_float4(0.f, 0.f, 0.f, 0.f);
        int gr = row0 + r;
        if (gr < M) v = *(const float4*)(X + (size_t)gr * K + c);
        *(float4*)(&Xs[r * (K + 4) + c]) = v;
    }
    __syncthreads();

    int cg = (t & 15) * 4;
    int rg = (t >> 4) * 4;

    float acc[4][4];
#pragma unroll
    for (int j = 0; j < 4; j++)
#pragma unroll
        for (int c = 0; c < 4; c++) acc[j][c] = 0.f;

#pragma unroll 4
    for (int k = 0; k < K; k++) {
        float4 w = *(float4*)(&Ws[k * 64 + cg]);
#pragma unroll
        for (int j = 0; j < 4; j++) {
            float xv = Xs[(rg + j) * (K + 4) + k];
            acc[j][0] = fmaf(xv, w.x, acc[j][0]);
            acc[j][1] = fmaf(xv, w.y, acc[j][1]);
            acc[j][2] = fmaf(xv, w.z, acc[j][2]);
            acc[j][3] = fmaf(xv, w.w, acc[j][3]);
        }
    }

#pragma unroll
    for (int j = 0; j < 4; j++) {
        int r = row0 + rg + j;
        if (r < M) {
            float d = dinv[r];
            float4 o = make_float4(acc[j][0] * d, acc[j][1] * d, acc[j][2] * d, acc[j][3] * d);
            *(float4*)(Y + (size_t)r * 64 + cg) = o;
        }
    }
}

// ---------------- pull aggregation + epilogue ----------------
__global__ __launch_bounds__(256) void aggregate_kernel(const float* __restrict__ hs,
                                                        const int* __restrict__ rowptr,
                                                        const int* __restrict__ csr,
                                                        const float* __restrict__ dinv,
                                                        const float* __restrict__ bias,
                                                        float* __restrict__ out, int N,
                                                        int do_relu) {
    int t = threadIdx.x;
    int node = blockIdx.x * 16 + (t >> 4);
    if (node >= N) return;
    int sub = t & 15;
    int gbase = t & 0x30;

    float4 acc = *(const float4*)(hs + (size_t)node * 64 + sub * 4);  // self-loop
    int e0 = rowptr[node];
    int e1 = rowptr[node + 1];

    int e = e0;
    for (; e + 16 <= e1; e += 16) {
        int idx = csr[e + sub];
#pragma unroll
        for (int j = 0; j < 16; ++j) {
            int s = __shfl(idx, gbase + j, 64);
            float4 v = *(const float4*)(hs + (size_t)s * 64 + sub * 4);
            acc.x += v.x;
            acc.y += v.y;
            acc.z += v.z;
            acc.w += v.w;
        }
    }
    for (; e < e1; ++e) {
        int s = csr[e];
        float4 v = *(const float4*)(hs + (size_t)s * 64 + sub * 4);
        acc.x += v.x;
        acc.y += v.y;
        acc.z += v.z;
        acc.w += v.w;
    }

    float d = dinv[node];
    float4 b = *(const float4*)(bias + sub * 4);
    float4 o = make_float4(fmaf(acc.x, d, b.x), fmaf(acc.y, d, b.y),
                           fmaf(acc.z, d, b.z), fmaf(acc.w, d, b.w));
    if (do_relu) {
        o.x = fmaxf(o.x, 0.f);
        o.y = fmaxf(o.y, 0.f);
        o.z = fmaxf(o.z, 0.f);
        o.w = fmaxf(o.w, 0.f);
    }
    *(float4*)(out + (size_t)node * 64 + sub * 4) = o;
}

// ---------------- launch ----------------
extern "C" void kernel_launch(void* const* d_in, const int* in_sizes, int n_in,
                              void* d_out, int out_size, void* d_ws, size_t ws_size,
                              hipStream_t stream) {
    const float* x  = (const float*)d_in[0];
    const int*   ei = (const int*)d_in[1];   // [2, E] int32
    const float* W1 = (const float*)d_in[2];
    const float* b1 = (const float*)d_in[3];
    const float* W2 = (const float*)d_in[4];
    const float* b2 = (const float*)d_in[5];

    const int N = in_sizes[0] / 128;  // 100000
    const int E = in_sizes[1] / 2;    // 3200000
    const int* src = ei;
    const int* dst = ei + E;
    float* out = (float*)d_out;

    const int nb   = (N + 127) >> BSHIFT;  // 782 buckets
    const int nblk = (E + CH - 1) / CH;    // 391 edge-chunk blocks

    char* ws = (char*)d_ws;
    size_t off = 0;
    auto alloc = [&](size_t bytes) -> char* {
        char* p = ws + off;
        off = (off + bytes + 255) & ~(size_t)255;
        return p;
    };
    // persistent
    int*   csr         = (int*)alloc((size_t)E * 4);
    int*   rowptr      = (int*)alloc((size_t)(N + 1) * 4);
    float* dinv        = (float*)alloc((size_t)N * 4);
    int*   bucketbase  = (int*)alloc((size_t)(nb + 1) * 4);
    int*   buckettotal = (int*)alloc((size_t)nb * 4);
    float* bufA        = (float*)alloc((size_t)N * 64 * 4);
    float* bufB        = (float*)alloc((size_t)N * 64 * 4);
    // transient (dead before gemm1 writes bufA) — alias into bufA/bufB region
    int* histmat = (int*)bufA;                          // nblk*nb*4 ~ 1.2 MB
    int* packed  = (int*)((char*)bufA + (size_t)nblk * nb * 4 + 256);  // E*4 = 12.8 MB

    hist_kernel<<<nblk, 256, 0, stream>>>(dst, histmat, E, nb);
    scancol_kernel<<<nb, 256, 0, stream>>>(histmat, histmat /*in-place*/, buckettotal, nb, nblk);
    scanbucket_kernel<<<1, 256, 0, stream>>>(buckettotal, bucketbase, nb, E);
    bscatter_kernel<<<nblk, 256, 0, stream>>>(src, dst, histmat, bucketbase, packed, E, nb);
    bcsr_kernel<<<nb, 256, 0, stream>>>(packed, bucketbase, rowptr, dinv, csr, N, nb);

    gemm_scaled<128><<<(N + 63) / 64, 256, 0, stream>>>(x, W1, dinv, bufA, N);
    aggregate_kernel<<<(N + 15) / 16, 256, 0, stream>>>(bufA, rowptr, csr, dinv, b1, bufB, N, 1);
    gemm_scaled<64><<<(N + 63) / 64, 256, 0, stream>>>(bufB, W2, dinv, bufA, N);
    aggregate_kernel<<<(N + 15) / 16, 256, 0, stream>>>(bufA, rowptr, csr, dinv, b2, out, N, 0);
}

// Round 4
// 355.799 us; speedup vs baseline: 2.3134x; 1.3371x over previous
//
#include <hip/hip_runtime.h>
#include <cstdint>

// ===================== GCN encoder on MI355X =====================
// out = gcn(relu(gcn(x, W1, b1)), W2, b2)
// gcn(x,W,b)[i] = dinv[i] * ( sum_{e: dst=i} (xW*dinv)[src] + (xW*dinv)[i] ) + b
// dinv = rsqrt(indeg+1) (self-loop), identical for both layers.
//
// R4: gather tables (h*dinv) stored BF16 -> one 128B cache line per edge
// gather (R3 was fetch-bound at 370 MB/aggregate, 3.4 TB/s). Accumulate fp32.
//
// Graph build with zero global atomics (two-level LDS bucket sort):
//  A. hist       B. scancol/scanbucket      C. bscatter (packed dst|src)
//  D. bcsr (rowptr + dinv + coalesced csr)
// Then gemm1(bf16 out) -> aggregate(relu, fp32 out) -> gemm2(bf16 out)
// -> aggregate -> d_out (fp32).

#define BSHIFT 7          // 128 nodes per bucket
#define NBMAX 784         // >= ceil(100000/128) = 782
#define CH 8192           // edges per block in passes A/C

// ---------------- bf16 helpers ----------------
__device__ inline unsigned short f2bf(float f) {
    unsigned u = __float_as_uint(f);
    unsigned r = (u + 0x7FFFu + ((u >> 16) & 1u)) >> 16;  // RNE
    return (unsigned short)r;
}
__device__ inline unsigned pack2(float a, float b) {
    return (unsigned)f2bf(a) | ((unsigned)f2bf(b) << 16);
}
__device__ inline float blo(unsigned u) { return __uint_as_float(u << 16); }
__device__ inline float bhi(unsigned u) { return __uint_as_float(u & 0xFFFF0000u); }

// ---------------- pass A: bucket histogram ----------------
__global__ __launch_bounds__(256) void hist_kernel(const int* __restrict__ dst,
                                                   int* __restrict__ histmat,
                                                   int E, int nb) {
    __shared__ int hist[NBMAX];
    int t = threadIdx.x;
    for (int b = t; b < nb; b += 256) hist[b] = 0;
    __syncthreads();
    int base = blockIdx.x * CH;
#pragma unroll
    for (int j = 0; j < CH / 1024; ++j) {
        int idx = base + j * 1024 + t * 4;
        if (idx + 4 <= E) {
            int4 d = *(const int4*)(dst + idx);
            atomicAdd(&hist[d.x >> BSHIFT], 1);
            atomicAdd(&hist[d.y >> BSHIFT], 1);
            atomicAdd(&hist[d.z >> BSHIFT], 1);
            atomicAdd(&hist[d.w >> BSHIFT], 1);
        } else {
            for (int k = 0; k < 4; ++k)
                if (idx + k < E) atomicAdd(&hist[dst[idx + k] >> BSHIFT], 1);
        }
    }
    __syncthreads();
    for (int b = t; b < nb; b += 256) histmat[blockIdx.x * nb + b] = hist[b];
}

// ---------------- pass B1: per-bucket scan over blocks ----------------
__global__ __launch_bounds__(256) void scancol_kernel(const int* __restrict__ histmat,
                                                      int* __restrict__ colbase,
                                                      int* __restrict__ buckettotal,
                                                      int nb, int nblk) {
    __shared__ int ts[256];
    int b = blockIdx.x;
    int t = threadIdx.x;
    int v[4];
    int tsum = 0;
#pragma unroll
    for (int k = 0; k < 4; ++k) {
        int blk = t * 4 + k;
        v[k] = (blk < nblk) ? histmat[blk * nb + b] : 0;
        tsum += v[k];
    }
    ts[t] = tsum;
    __syncthreads();
    for (int ofs = 1; ofs < 256; ofs <<= 1) {
        int val = (t >= ofs) ? ts[t - ofs] : 0;
        __syncthreads();
        ts[t] += val;
        __syncthreads();
    }
    int run = ts[t] - tsum;
#pragma unroll
    for (int k = 0; k < 4; ++k) {
        int blk = t * 4 + k;
        if (blk < nblk) colbase[blk * nb + b] = run;
        run += v[k];
    }
    if (t == 255) buckettotal[b] = ts[255];
}

// ---------------- pass B2: scan bucket totals (single block) ----------------
__global__ __launch_bounds__(256) void scanbucket_kernel(const int* __restrict__ buckettotal,
                                                         int* __restrict__ bucketbase,
                                                         int nb, int E) {
    __shared__ int ts[256];
    int t = threadIdx.x;
    int v[4];
    int tsum = 0;
#pragma unroll
    for (int k = 0; k < 4; ++k) {
        int b = t * 4 + k;
        v[k] = (b < nb) ? buckettotal[b] : 0;
        tsum += v[k];
    }
    ts[t] = tsum;
    __syncthreads();
    for (int ofs = 1; ofs < 256; ofs <<= 1) {
        int val = (t >= ofs) ? ts[t - ofs] : 0;
        __syncthreads();
        ts[t] += val;
        __syncthreads();
    }
    int run = ts[t] - tsum;
#pragma unroll
    for (int k = 0; k < 4; ++k) {
        int b = t * 4 + k;
        if (b < nb) bucketbase[b] = run;
        run += v[k];
    }
    if (t == 0) bucketbase[nb] = E;
}

// ---------------- pass C: scatter into bucket regions (LDS cursors) ---------
__global__ __launch_bounds__(256) void bscatter_kernel(const int* __restrict__ src,
                                                       const int* __restrict__ dst,
                                                       const int* __restrict__ colbase,
                                                       const int* __restrict__ bucketbase,
                                                       int* __restrict__ packed,
                                                       int E, int nb) {
    __shared__ int cur[NBMAX];
    int t = threadIdx.x;
    for (int b = t; b < nb; b += 256)
        cur[b] = bucketbase[b] + colbase[blockIdx.x * nb + b];
    __syncthreads();
    int base = blockIdx.x * CH;
#pragma unroll
    for (int j = 0; j < CH / 1024; ++j) {
        int idx = base + j * 1024 + t * 4;
        if (idx + 4 <= E) {
            int4 d = *(const int4*)(dst + idx);
            int4 s = *(const int4*)(src + idx);
            int p;
            p = atomicAdd(&cur[d.x >> BSHIFT], 1); packed[p] = ((d.x & 127) << 17) | s.x;
            p = atomicAdd(&cur[d.y >> BSHIFT], 1); packed[p] = ((d.y & 127) << 17) | s.y;
            p = atomicAdd(&cur[d.z >> BSHIFT], 1); packed[p] = ((d.z & 127) << 17) | s.z;
            p = atomicAdd(&cur[d.w >> BSHIFT], 1); packed[p] = ((d.w & 127) << 17) | s.w;
        } else {
            for (int k = 0; k < 4; ++k)
                if (idx + k < E) {
                    int dd = dst[idx + k], ss = src[idx + k];
                    int p = atomicAdd(&cur[dd >> BSHIFT], 1);
                    packed[p] = ((dd & 127) << 17) | ss;
                }
        }
    }
}

// ---------------- pass D: within-bucket CSR + rowptr + dinv ----------------
__global__ __launch_bounds__(256) void bcsr_kernel(const int* __restrict__ packed,
                                                   const int* __restrict__ bucketbase,
                                                   int* __restrict__ rowptr,
                                                   float* __restrict__ dinv,
                                                   int* __restrict__ csr,
                                                   int N, int nb) {
    __shared__ int deg[128];
    __shared__ int lrp[128];
    __shared__ int ts[128];
    int b = blockIdx.x;
    int t = threadIdx.x;
    if (t < 128) deg[t] = 0;
    __syncthreads();
    int bb0 = bucketbase[b];
    int bb1 = bucketbase[b + 1];
    for (int i = bb0 + t; i < bb1; i += 256)
        atomicAdd(&deg[packed[i] >> 17], 1);
    __syncthreads();
    if (t < 128) ts[t] = deg[t];
    __syncthreads();
    for (int ofs = 1; ofs < 128; ofs <<= 1) {
        int v = (t < 128 && t >= ofs) ? ts[t - ofs] : 0;
        __syncthreads();
        if (t < 128) ts[t] += v;
        __syncthreads();
    }
    int node0 = b << BSHIFT;
    int nlocal = min(128, N - node0);
    if (t < 128) lrp[t] = ts[t] - deg[t];
    if (t < nlocal) {
        rowptr[node0 + t] = bb0 + (ts[t] - deg[t]);
        dinv[node0 + t] = rsqrtf((float)(deg[t] + 1));
    }
    if (t == nlocal) rowptr[node0 + nlocal] = bb1;
    __syncthreads();
    for (int i = bb0 + t; i < bb1; i += 256) {
        int v = packed[i];
        int p = atomicAdd(&lrp[v >> 17], 1);
        csr[bb0 + p] = v & 0x1FFFF;
    }
}

// ------- GEMM: Ybf[M,64](bf16) = (X[M,K] @ W[K,64]) * dinv[row] -------
template <int K>
__global__ __launch_bounds__(256) void gemm_scaled(const float* __restrict__ X,
                                                   const float* __restrict__ W,
                                                   const float* __restrict__ dinv,
                                                   unsigned short* __restrict__ Ybf, int M) {
    __shared__ float Ws[K * 64];
    __shared__ float Xs[64 * (K + 4)];
    int t = threadIdx.x;

    for (int i = t; i < K * 64 / 4; i += 256)
        ((float4*)Ws)[i] = ((const float4*)W)[i];

    int row0 = blockIdx.x * 64;
    for (int i = t; i < 64 * K / 4; i += 256) {
        int idx = i * 4;
        int r = idx / K;
        int c = idx - r * K;
        float4 v = make_float4(0.f, 0.f, 0.f, 0.f);
        int gr = row0 + r;
        if (gr < M) v = *(const float4*)(X + (size_t)gr * K + c);
        *(float4*)(&Xs[r * (K + 4) + c]) = v;
    }
    __syncthreads();

    int cg = (t & 15) * 4;
    int rg = (t >> 4) * 4;

    float acc[4][4];
#pragma unroll
    for (int j = 0; j < 4; j++)
#pragma unroll
        for (int c = 0; c < 4; c++) acc[j][c] = 0.f;

#pragma unroll 4
    for (int k = 0; k < K; k++) {
        float4 w = *(float4*)(&Ws[k * 64 + cg]);
#pragma unroll
        for (int j = 0; j < 4; j++) {
            float xv = Xs[(rg + j) * (K + 4) + k];
            acc[j][0] = fmaf(xv, w.x, acc[j][0]);
            acc[j][1] = fmaf(xv, w.y, acc[j][1]);
            acc[j][2] = fmaf(xv, w.z, acc[j][2]);
            acc[j][3] = fmaf(xv, w.w, acc[j][3]);
        }
    }

#pragma unroll
    for (int j = 0; j < 4; j++) {
        int r = row0 + rg + j;
        if (r < M) {
            float d = dinv[r];
            uint2 o;
            o.x = pack2(acc[j][0] * d, acc[j][1] * d);
            o.y = pack2(acc[j][2] * d, acc[j][3] * d);
            *(uint2*)(Ybf + (size_t)r * 64 + cg) = o;
        }
    }
}

// ---------------- pull aggregation + epilogue ----------------
// 8 lanes per node, one uint4 (8 bf16 feats) per lane; fp32 accumulate.
// CSR indices fetched 8-at-a-time per group, broadcast via shfl -> 8
// independent 128B line gathers in flight per batch.
__global__ __launch_bounds__(256) void aggregate_kernel(const unsigned* __restrict__ hsu,
                                                        const int* __restrict__ rowptr,
                                                        const int* __restrict__ csr,
                                                        const float* __restrict__ dinv,
                                                        const float* __restrict__ bias,
                                                        float* __restrict__ out, int N,
                                                        int do_relu) {
    int t = threadIdx.x;
    int node = blockIdx.x * 32 + (t >> 3);
    if (node >= N) return;
    int sub = t & 7;       // lane within 8-lane group; features sub*8..sub*8+7
    int gbase = t & 56;    // group base lane within wave

    float acc[8];
    {
        uint4 v = *(const uint4*)(hsu + (size_t)node * 32 + sub * 4);  // self-loop
        acc[0] = blo(v.x); acc[1] = bhi(v.x);
        acc[2] = blo(v.y); acc[3] = bhi(v.y);
        acc[4] = blo(v.z); acc[5] = bhi(v.z);
        acc[6] = blo(v.w); acc[7] = bhi(v.w);
    }
    int e0 = rowptr[node];
    int e1 = rowptr[node + 1];

    int e = e0;
    for (; e + 8 <= e1; e += 8) {
        int idx = csr[e + sub];
#pragma unroll
        for (int j = 0; j < 8; ++j) {
            int s = __shfl(idx, gbase + j, 64);
            uint4 v = *(const uint4*)(hsu + (size_t)s * 32 + sub * 4);
            acc[0] += blo(v.x); acc[1] += bhi(v.x);
            acc[2] += blo(v.y); acc[3] += bhi(v.y);
            acc[4] += blo(v.z); acc[5] += bhi(v.z);
            acc[6] += blo(v.w); acc[7] += bhi(v.w);
        }
    }
    for (; e < e1; ++e) {
        int s = csr[e];
        uint4 v = *(const uint4*)(hsu + (size_t)s * 32 + sub * 4);
        acc[0] += blo(v.x); acc[1] += bhi(v.x);
        acc[2] += blo(v.y); acc[3] += bhi(v.y);
        acc[4] += blo(v.z); acc[5] += bhi(v.z);
        acc[6] += blo(v.w); acc[7] += bhi(v.w);
    }

    float d = dinv[node];
    float4 b0 = *(const float4*)(bias + sub * 8);
    float4 b1 = *(const float4*)(bias + sub * 8 + 4);
    float o[8];
    o[0] = fmaf(acc[0], d, b0.x); o[1] = fmaf(acc[1], d, b0.y);
    o[2] = fmaf(acc[2], d, b0.z); o[3] = fmaf(acc[3], d, b0.w);
    o[4] = fmaf(acc[4], d, b1.x); o[5] = fmaf(acc[5], d, b1.y);
    o[6] = fmaf(acc[6], d, b1.z); o[7] = fmaf(acc[7], d, b1.w);
    if (do_relu) {
#pragma unroll
        for (int k = 0; k < 8; ++k) o[k] = fmaxf(o[k], 0.f);
    }
    float* op = out + (size_t)node * 64 + sub * 8;
    *(float4*)(op)     = make_float4(o[0], o[1], o[2], o[3]);
    *(float4*)(op + 4) = make_float4(o[4], o[5], o[6], o[7]);
}

// ---------------- launch ----------------
extern "C" void kernel_launch(void* const* d_in, const int* in_sizes, int n_in,
                              void* d_out, int out_size, void* d_ws, size_t ws_size,
                              hipStream_t stream) {
    const float* x  = (const float*)d_in[0];
    const int*   ei = (const int*)d_in[1];   // [2, E] int32
    const float* W1 = (const float*)d_in[2];
    const float* b1 = (const float*)d_in[3];
    const float* W2 = (const float*)d_in[4];
    const float* b2 = (const float*)d_in[5];

    const int N = in_sizes[0] / 128;  // 100000
    const int E = in_sizes[1] / 2;    // 3200000
    const int* src = ei;
    const int* dst = ei + E;
    float* out = (float*)d_out;

    const int nb   = (N + 127) >> BSHIFT;  // 782
    const int nblk = (E + CH - 1) / CH;    // 391

    char* ws = (char*)d_ws;
    size_t off = 0;
    auto alloc = [&](size_t bytes) -> char* {
        char* p = ws + off;
        off = (off + bytes + 255) & ~(size_t)255;
        return p;
    };
    // persistent
    int*   csr         = (int*)alloc((size_t)E * 4);
    int*   rowptr      = (int*)alloc((size_t)(N + 1) * 4);
    float* dinv        = (float*)alloc((size_t)N * 4);
    int*   bucketbase  = (int*)alloc((size_t)(nb + 1) * 4);
    int*   buckettotal = (int*)alloc((size_t)nb * 4);
    unsigned short* bufA = (unsigned short*)alloc((size_t)N * 64 * 2);  // bf16 h*dinv
    float* bufB        = (float*)alloc((size_t)N * 64 * 4);             // fp32 relu(agg)
    // transient (dead before gemm1 writes bufA) — alias bufA+bufB region
    int* histmat = (int*)bufA;                                        // ~1.2 MB
    int* packed  = (int*)((char*)bufA + (size_t)nblk * nb * 4 + 256); // E*4, spills into bufB

    hist_kernel<<<nblk, 256, 0, stream>>>(dst, histmat, E, nb);
    scancol_kernel<<<nb, 256, 0, stream>>>(histmat, histmat, buckettotal, nb, nblk);
    scanbucket_kernel<<<1, 256, 0, stream>>>(buckettotal, bucketbase, nb, E);
    bscatter_kernel<<<nblk, 256, 0, stream>>>(src, dst, histmat, bucketbase, packed, E, nb);
    bcsr_kernel<<<nb, 256, 0, stream>>>(packed, bucketbase, rowptr, dinv, csr, N, nb);

    gemm_scaled<128><<<(N + 63) / 64, 256, 0, stream>>>(x, W1, dinv, bufA, N);
    aggregate_kernel<<<(N + 31) / 32, 256, 0, stream>>>((const unsigned*)bufA, rowptr, csr,
                                                        dinv, b1, bufB, N, 1);
    gemm_scaled<64><<<(N + 63) / 64, 256, 0, stream>>>(bufB, W2, dinv, bufA, N);
    aggregate_kernel<<<(N + 31) / 32, 256, 0, stream>>>((const unsigned*)bufA, rowptr, csr,
                                                        dinv, b2, out, N, 0);
}

// Round 5
// 321.182 us; speedup vs baseline: 2.5628x; 1.1078x over previous
//
#include <hip/hip_runtime.h>
#include <cstdint>

// ===================== GCN encoder on MI355X =====================
// out = gcn(relu(gcn(x, W1, b1)), W2, b2)
// gcn(x,W,b)[i] = dinv[i] * ( sum_{e: dst=i} (xW*dinv)[src] + (xW*dinv)[i] ) + b
// dinv = rsqrt(indeg+1) (self-loop), identical for both layers.
//
// R5: GEMMs use MFMA bf16 (16x16x32); gather tables and inter-layer buffer
// all bf16. Graph build (zero global atomics, two-level LDS bucket sort)
// unchanged from R3/R4.

#define BSHIFT 7          // 128 nodes per bucket
#define NBMAX 784         // >= ceil(100000/128) = 782
#define CH 8192           // edges per block in passes A/C

typedef __attribute__((ext_vector_type(8))) short bf16x8;
typedef __attribute__((ext_vector_type(4))) float f32x4;

// ---------------- bf16 helpers ----------------
__device__ inline unsigned short f2bf(float f) {
    unsigned u = __float_as_uint(f);
    unsigned r = (u + 0x7FFFu + ((u >> 16) & 1u)) >> 16;  // RNE
    return (unsigned short)r;
}
__device__ inline unsigned pack2(float a, float b) {
    return (unsigned)f2bf(a) | ((unsigned)f2bf(b) << 16);
}
__device__ inline float blo(unsigned u) { return __uint_as_float(u << 16); }
__device__ inline float bhi(unsigned u) { return __uint_as_float(u & 0xFFFF0000u); }

// ---------------- weight prep: W[K][64] fp32 -> Wt[64][K] bf16 ----------------
__global__ __launch_bounds__(256) void wprep_kernel(const float* __restrict__ W1,
                                                    const float* __restrict__ W2,
                                                    unsigned short* __restrict__ W1t,
                                                    unsigned short* __restrict__ W2t) {
    int i = blockIdx.x * 256 + threadIdx.x;
    if (i < 128 * 64) {
        int k = i >> 6, n = i & 63;
        W1t[n * 128 + k] = f2bf(W1[i]);
    }
    int j = i - 128 * 64;
    if (j >= 0 && j < 64 * 64) {
        int k = j >> 6, n = j & 63;
        W2t[n * 64 + k] = f2bf(W2[j]);
    }
}

// ---------------- pass A: bucket histogram ----------------
__global__ __launch_bounds__(256) void hist_kernel(const int* __restrict__ dst,
                                                   int* __restrict__ histmat,
                                                   int E, int nb) {
    __shared__ int hist[NBMAX];
    int t = threadIdx.x;
    for (int b = t; b < nb; b += 256) hist[b] = 0;
    __syncthreads();
    int base = blockIdx.x * CH;
#pragma unroll
    for (int j = 0; j < CH / 1024; ++j) {
        int idx = base + j * 1024 + t * 4;
        if (idx + 4 <= E) {
            int4 d = *(const int4*)(dst + idx);
            atomicAdd(&hist[d.x >> BSHIFT], 1);
            atomicAdd(&hist[d.y >> BSHIFT], 1);
            atomicAdd(&hist[d.z >> BSHIFT], 1);
            atomicAdd(&hist[d.w >> BSHIFT], 1);
        } else {
            for (int k = 0; k < 4; ++k)
                if (idx + k < E) atomicAdd(&hist[dst[idx + k] >> BSHIFT], 1);
        }
    }
    __syncthreads();
    for (int b = t; b < nb; b += 256) histmat[blockIdx.x * nb + b] = hist[b];
}

// ---------------- pass B1: per-bucket scan over blocks ----------------
__global__ __launch_bounds__(256) void scancol_kernel(const int* __restrict__ histmat,
                                                      int* __restrict__ colbase,
                                                      int* __restrict__ buckettotal,
                                                      int nb, int nblk) {
    __shared__ int ts[256];
    int b = blockIdx.x;
    int t = threadIdx.x;
    int v[4];
    int tsum = 0;
#pragma unroll
    for (int k = 0; k < 4; ++k) {
        int blk = t * 4 + k;
        v[k] = (blk < nblk) ? histmat[blk * nb + b] : 0;
        tsum += v[k];
    }
    ts[t] = tsum;
    __syncthreads();
    for (int ofs = 1; ofs < 256; ofs <<= 1) {
        int val = (t >= ofs) ? ts[t - ofs] : 0;
        __syncthreads();
        ts[t] += val;
        __syncthreads();
    }
    int run = ts[t] - tsum;
#pragma unroll
    for (int k = 0; k < 4; ++k) {
        int blk = t * 4 + k;
        if (blk < nblk) colbase[blk * nb + b] = run;
        run += v[k];
    }
    if (t == 255) buckettotal[b] = ts[255];
}

// ---------------- pass B2: scan bucket totals (single block) ----------------
__global__ __launch_bounds__(256) void scanbucket_kernel(const int* __restrict__ buckettotal,
                                                         int* __restrict__ bucketbase,
                                                         int nb, int E) {
    __shared__ int ts[256];
    int t = threadIdx.x;
    int v[4];
    int tsum = 0;
#pragma unroll
    for (int k = 0; k < 4; ++k) {
        int b = t * 4 + k;
        v[k] = (b < nb) ? buckettotal[b] : 0;
        tsum += v[k];
    }
    ts[t] = tsum;
    __syncthreads();
    for (int ofs = 1; ofs < 256; ofs <<= 1) {
        int val = (t >= ofs) ? ts[t - ofs] : 0;
        __syncthreads();
        ts[t] += val;
        __syncthreads();
    }
    int run = ts[t] - tsum;
#pragma unroll
    for (int k = 0; k < 4; ++k) {
        int b = t * 4 + k;
        if (b < nb) bucketbase[b] = run;
        run += v[k];
    }
    if (t == 0) bucketbase[nb] = E;
}

// ---------------- pass C: scatter into bucket regions (LDS cursors) ---------
__global__ __launch_bounds__(256) void bscatter_kernel(const int* __restrict__ src,
                                                       const int* __restrict__ dst,
                                                       const int* __restrict__ colbase,
                                                       const int* __restrict__ bucketbase,
                                                       int* __restrict__ packed,
                                                       int E, int nb) {
    __shared__ int cur[NBMAX];
    int t = threadIdx.x;
    for (int b = t; b < nb; b += 256)
        cur[b] = bucketbase[b] + colbase[blockIdx.x * nb + b];
    __syncthreads();
    int base = blockIdx.x * CH;
#pragma unroll
    for (int j = 0; j < CH / 1024; ++j) {
        int idx = base + j * 1024 + t * 4;
        if (idx + 4 <= E) {
            int4 d = *(const int4*)(dst + idx);
            int4 s = *(const int4*)(src + idx);
            int p;
            p = atomicAdd(&cur[d.x >> BSHIFT], 1); packed[p] = ((d.x & 127) << 17) | s.x;
            p = atomicAdd(&cur[d.y >> BSHIFT], 1); packed[p] = ((d.y & 127) << 17) | s.y;
            p = atomicAdd(&cur[d.z >> BSHIFT], 1); packed[p] = ((d.z & 127) << 17) | s.z;
            p = atomicAdd(&cur[d.w >> BSHIFT], 1); packed[p] = ((d.w & 127) << 17) | s.w;
        } else {
            for (int k = 0; k < 4; ++k)
                if (idx + k < E) {
                    int dd = dst[idx + k], ss = src[idx + k];
                    int p = atomicAdd(&cur[dd >> BSHIFT], 1);
                    packed[p] = ((dd & 127) << 17) | ss;
                }
        }
    }
}

// ---------------- pass D: within-bucket CSR + rowptr + dinv ----------------
__global__ __launch_bounds__(256) void bcsr_kernel(const int* __restrict__ packed,
                                                   const int* __restrict__ bucketbase,
                                                   int* __restrict__ rowptr,
                                                   float* __restrict__ dinv,
                                                   int* __restrict__ csr,
                                                   int N, int nb) {
    __shared__ int deg[128];
    __shared__ int lrp[128];
    __shared__ int ts[128];
    int b = blockIdx.x;
    int t = threadIdx.x;
    if (t < 128) deg[t] = 0;
    __syncthreads();
    int bb0 = bucketbase[b];
    int bb1 = bucketbase[b + 1];
    for (int i = bb0 + t; i < bb1; i += 256)
        atomicAdd(&deg[packed[i] >> 17], 1);
    __syncthreads();
    if (t < 128) ts[t] = deg[t];
    __syncthreads();
    for (int ofs = 1; ofs < 128; ofs <<= 1) {
        int v = (t < 128 && t >= ofs) ? ts[t - ofs] : 0;
        __syncthreads();
        if (t < 128) ts[t] += v;
        __syncthreads();
    }
    int node0 = b << BSHIFT;
    int nlocal = min(128, N - node0);
    if (t < 128) lrp[t] = ts[t] - deg[t];
    if (t < nlocal) {
        rowptr[node0 + t] = bb0 + (ts[t] - deg[t]);
        dinv[node0 + t] = rsqrtf((float)(deg[t] + 1));
    }
    if (t == nlocal) rowptr[node0 + nlocal] = bb1;
    __syncthreads();
    for (int i = bb0 + t; i < bb1; i += 256) {
        int v = packed[i];
        int p = atomicAdd(&lrp[v >> 17], 1);
        csr[bb0 + p] = v & 0x1FFFF;
    }
}

// ------- MFMA GEMM: Ybf[M,64](bf16) = (X[M,K] @ W[K,64]) * dinv[row] -------
// 64 rows/block, 256 thr = 4 waves; wave w computes rows 16w..16w+15 x all 64
// cols via 4 mfma_f32_16x16x32_bf16 accumulators over K/32 steps.
// A-frag: A[m=lane&15][k=s*32+(lane>>4)*8+j] from Xs (row-major, KP pad).
// B-frag: B[k][n] = Wt[n=lane&15][k] (pre-transposed) — both contiguous b128.
// C/D: col=lane&15, row=(lane>>4)*4+reg (m89-verified). Epilogue via LDS for
// coalesced bf16 stores.
template <int K, bool XBF16>
__global__ __launch_bounds__(256) void gemm_mfma(const void* __restrict__ Xv,
                                                 const unsigned short* __restrict__ Wt,
                                                 const float* __restrict__ dinv,
                                                 unsigned short* __restrict__ Ybf, int M) {
    constexpr int KP = K + 8;  // padded row stride (shorts); keeps 16B align
    __shared__ unsigned short Xs[64 * KP];   // also reused as Cs (64*72 fits)
    __shared__ unsigned short Ws[64 * KP];
    int t = threadIdx.x;
    int row0 = blockIdx.x * 64;

    for (int i = t; i < 64 * K / 8; i += 256) {
        int r = i / (K / 8), c8 = i % (K / 8);
        *(uint4*)(&Ws[r * KP + c8 * 8]) = ((const uint4*)Wt)[i];
    }
    if (XBF16) {
        const unsigned short* X = (const unsigned short*)Xv;
        for (int i = t; i < 64 * K / 8; i += 256) {
            int r = i / (K / 8), c8 = i % (K / 8);
            int gr = row0 + r;
            uint4 v = make_uint4(0u, 0u, 0u, 0u);
            if (gr < M) v = ((const uint4*)(X + (size_t)gr * K))[c8];
            *(uint4*)(&Xs[r * KP + c8 * 8]) = v;
        }
    } else {
        const float* X = (const float*)Xv;
        for (int i = t; i < 64 * K / 4; i += 256) {
            int r = i / (K / 4), c4 = i % (K / 4);
            int gr = row0 + r;
            float4 v = make_float4(0.f, 0.f, 0.f, 0.f);
            if (gr < M) v = ((const float4*)(X + (size_t)gr * K))[c4];
            uint2 p;
            p.x = pack2(v.x, v.y);
            p.y = pack2(v.z, v.w);
            *(uint2*)(&Xs[r * KP + c4 * 4]) = p;
        }
    }
    __syncthreads();

    int lane = t & 63;
    int w = t >> 6;
    int m = lane & 15;
    int q = lane >> 4;

    f32x4 acc[4];
#pragma unroll
    for (int nt = 0; nt < 4; ++nt) acc[nt] = (f32x4){0.f, 0.f, 0.f, 0.f};

#pragma unroll
    for (int s = 0; s < K / 32; ++s) {
        bf16x8 a = *(const bf16x8*)(&Xs[(16 * w + m) * KP + s * 32 + q * 8]);
#pragma unroll
        for (int nt = 0; nt < 4; ++nt) {
            bf16x8 b = *(const bf16x8*)(&Ws[(16 * nt + m) * KP + s * 32 + q * 8]);
            acc[nt] = __builtin_amdgcn_mfma_f32_16x16x32_bf16(a, b, acc[nt], 0, 0, 0);
        }
    }
    __syncthreads();  // done reading Xs/Ws; reuse Xs as C staging

    unsigned short* Cs = Xs;  // stride 72 shorts (16B-aligned rows)
#pragma unroll
    for (int nt = 0; nt < 4; ++nt)
#pragma unroll
        for (int r = 0; r < 4; ++r) {
            int row = 16 * w + q * 4 + r;
            int gr = row0 + row;
            float d = (gr < M) ? dinv[gr] : 0.f;
            Cs[row * 72 + nt * 16 + m] = f2bf(acc[nt][r] * d);
        }
    __syncthreads();
    for (int i = t; i < 64 * 64 / 8; i += 256) {
        int r = i >> 3, c8 = i & 7;
        int gr = row0 + r;
        if (gr < M)
            *(uint4*)(Ybf + (size_t)gr * 64 + c8 * 8) = *(const uint4*)(&Cs[r * 72 + c8 * 8]);
    }
}

// ---------------- pull aggregation + epilogue ----------------
// 8 lanes per node, one uint4 (8 bf16 feats) per lane; fp32 accumulate.
// obf: write bf16 (inter-layer) else fp32 (final output).
__global__ __launch_bounds__(256) void aggregate_kernel(const unsigned* __restrict__ hsu,
                                                        const int* __restrict__ rowptr,
                                                        const int* __restrict__ csr,
                                                        const float* __restrict__ dinv,
                                                        const float* __restrict__ bias,
                                                        void* __restrict__ outv, int N,
                                                        int do_relu, int obf) {
    int t = threadIdx.x;
    int node = blockIdx.x * 32 + (t >> 3);
    if (node >= N) return;
    int sub = t & 7;
    int gbase = t & 56;

    float acc[8];
    {
        uint4 v = *(const uint4*)(hsu + (size_t)node * 32 + sub * 4);  // self-loop
        acc[0] = blo(v.x); acc[1] = bhi(v.x);
        acc[2] = blo(v.y); acc[3] = bhi(v.y);
        acc[4] = blo(v.z); acc[5] = bhi(v.z);
        acc[6] = blo(v.w); acc[7] = bhi(v.w);
    }
    int e0 = rowptr[node];
    int e1 = rowptr[node + 1];

    int e = e0;
    for (; e + 8 <= e1; e += 8) {
        int idx = csr[e + sub];
#pragma unroll
        for (int j = 0; j < 8; ++j) {
            int s = __shfl(idx, gbase + j, 64);
            uint4 v = *(const uint4*)(hsu + (size_t)s * 32 + sub * 4);
            acc[0] += blo(v.x); acc[1] += bhi(v.x);
            acc[2] += blo(v.y); acc[3] += bhi(v.y);
            acc[4] += blo(v.z); acc[5] += bhi(v.z);
            acc[6] += blo(v.w); acc[7] += bhi(v.w);
        }
    }
    for (; e < e1; ++e) {
        int s = csr[e];
        uint4 v = *(const uint4*)(hsu + (size_t)s * 32 + sub * 4);
        acc[0] += blo(v.x); acc[1] += bhi(v.x);
        acc[2] += blo(v.y); acc[3] += bhi(v.y);
        acc[4] += blo(v.z); acc[5] += bhi(v.z);
        acc[6] += blo(v.w); acc[7] += bhi(v.w);
    }

    float d = dinv[node];
    float4 b0 = *(const float4*)(bias + sub * 8);
    float4 b1 = *(const float4*)(bias + sub * 8 + 4);
    float o[8];
    o[0] = fmaf(acc[0], d, b0.x); o[1] = fmaf(acc[1], d, b0.y);
    o[2] = fmaf(acc[2], d, b0.z); o[3] = fmaf(acc[3], d, b0.w);
    o[4] = fmaf(acc[4], d, b1.x); o[5] = fmaf(acc[5], d, b1.y);
    o[6] = fmaf(acc[6], d, b1.z); o[7] = fmaf(acc[7], d, b1.w);
    if (do_relu) {
#pragma unroll
        for (int k = 0; k < 8; ++k) o[k] = fmaxf(o[k], 0.f);
    }
    if (obf) {
        unsigned short* outb = (unsigned short*)outv;
        uint4 p;
        p.x = pack2(o[0], o[1]); p.y = pack2(o[2], o[3]);
        p.z = pack2(o[4], o[5]); p.w = pack2(o[6], o[7]);
        *(uint4*)(outb + (size_t)node * 64 + sub * 8) = p;
    } else {
        float* op = (float*)outv + (size_t)node * 64 + sub * 8;
        *(float4*)(op)     = make_float4(o[0], o[1], o[2], o[3]);
        *(float4*)(op + 4) = make_float4(o[4], o[5], o[6], o[7]);
    }
}

// ---------------- launch ----------------
extern "C" void kernel_launch(void* const* d_in, const int* in_sizes, int n_in,
                              void* d_out, int out_size, void* d_ws, size_t ws_size,
                              hipStream_t stream) {
    const float* x  = (const float*)d_in[0];
    const int*   ei = (const int*)d_in[1];   // [2, E] int32
    const float* W1 = (const float*)d_in[2];
    const float* b1 = (const float*)d_in[3];
    const float* W2 = (const float*)d_in[4];
    const float* b2 = (const float*)d_in[5];

    const int N = in_sizes[0] / 128;  // 100000
    const int E = in_sizes[1] / 2;    // 3200000
    const int* src = ei;
    const int* dst = ei + E;
    float* out = (float*)d_out;

    const int nb   = (N + 127) >> BSHIFT;  // 782
    const int nblk = (E + CH - 1) / CH;    // 391

    char* ws = (char*)d_ws;
    size_t off = 0;
    auto alloc = [&](size_t bytes) -> char* {
        char* p = ws + off;
        off = (off + bytes + 255) & ~(size_t)255;
        return p;
    };
    // persistent
    int*   csr         = (int*)alloc((size_t)E * 4);
    int*   rowptr      = (int*)alloc((size_t)(N + 1) * 4);
    float* dinv        = (float*)alloc((size_t)N * 4);
    int*   bucketbase  = (int*)alloc((size_t)(nb + 1) * 4);
    int*   buckettotal = (int*)alloc((size_t)nb * 4);
    unsigned short* W1t = (unsigned short*)alloc(64 * 128 * 2);
    unsigned short* W2t = (unsigned short*)alloc(64 * 64 * 2);
    unsigned short* bufA = (unsigned short*)alloc((size_t)N * 64 * 2);  // bf16 h*dinv
    unsigned short* bufB = (unsigned short*)alloc((size_t)N * 64 * 2);  // bf16 relu(agg1)
    // transient (dead before gemm1 writes bufA) — alias bufA+bufB region
    int* histmat = (int*)bufA;                                        // ~1.2 MB
    int* packed  = (int*)((char*)bufA + (size_t)nblk * nb * 4 + 256); // E*4, spills into bufB

    wprep_kernel<<<(128 * 64 + 64 * 64 + 255) / 256, 256, 0, stream>>>(W1, W2, W1t, W2t);
    hist_kernel<<<nblk, 256, 0, stream>>>(dst, histmat, E, nb);
    scancol_kernel<<<nb, 256, 0, stream>>>(histmat, histmat, buckettotal, nb, nblk);
    scanbucket_kernel<<<1, 256, 0, stream>>>(buckettotal, bucketbase, nb, E);
    bscatter_kernel<<<nblk, 256, 0, stream>>>(src, dst, histmat, bucketbase, packed, E, nb);
    bcsr_kernel<<<nb, 256, 0, stream>>>(packed, bucketbase, rowptr, dinv, csr, N, nb);

    gemm_mfma<128, false><<<(N + 63) / 64, 256, 0, stream>>>(x, W1t, dinv, bufA, N);
    aggregate_kernel<<<(N + 31) / 32, 256, 0, stream>>>((const unsigned*)bufA, rowptr, csr,
                                                        dinv, b1, bufB, N, 1, 1);
    gemm_mfma<64, true><<<(N + 63) / 64, 256, 0, stream>>>(bufB, W2t, dinv, bufA, N);
    aggregate_kernel<<<(N + 31) / 32, 256, 0, stream>>>((const unsigned*)bufA, rowptr, csr,
                                                        dinv, b2, out, N, 0, 0);
}

// Round 6
// 318.768 us; speedup vs baseline: 2.5822x; 1.0076x over previous
//
#include <hip/hip_runtime.h>
#include <cstdint>

// ===================== GCN encoder on MI355X =====================
// out = gcn(relu(gcn(x, W1, b1)), W2, b2)
// gcn(x,W,b)[i] = dinv[i] * ( sum_{e: dst=i} (xW*dinv)[src] + (xW*dinv)[i] ) + b
// dinv = rsqrt(indeg+1) (self-loop), identical for both layers.
//
// R6: build-phase overhaul — CH 8192->4096 (3 blk/CU for hist/bscatter),
// bcsr builds CSR in LDS (single global read of packed, coalesced csr write),
// wprep folded into hist. MFMA GEMMs + bf16 gather tables from R5 unchanged.

#define BSHIFT 7          // 128 nodes per bucket
#define NBMAX 784         // >= ceil(100000/128) = 782
#define CH 4096           // edges per block in passes A/C
#define MAXB 6016         // LDS-cached bucket capacity (avg 4096, +30 sigma)

typedef __attribute__((ext_vector_type(8))) short bf16x8;
typedef __attribute__((ext_vector_type(4))) float f32x4;

// ---------------- bf16 helpers ----------------
__device__ inline unsigned short f2bf(float f) {
    unsigned u = __float_as_uint(f);
    unsigned r = (u + 0x7FFFu + ((u >> 16) & 1u)) >> 16;  // RNE
    return (unsigned short)r;
}
__device__ inline unsigned pack2(float a, float b) {
    return (unsigned)f2bf(a) | ((unsigned)f2bf(b) << 16);
}
__device__ inline float blo(unsigned u) { return __uint_as_float(u << 16); }
__device__ inline float bhi(unsigned u) { return __uint_as_float(u & 0xFFFF0000u); }

// ---------------- pass A: bucket histogram (+ folded weight prep) ----------
__global__ __launch_bounds__(256) void hist_kernel(const int* __restrict__ dst,
                                                   int* __restrict__ histmat,
                                                   int E, int nb, int nblk,
                                                   const float* __restrict__ W1,
                                                   const float* __restrict__ W2,
                                                   unsigned short* __restrict__ W1t,
                                                   unsigned short* __restrict__ W2t) {
    if (blockIdx.x >= (unsigned)nblk) {
        // weight-prep blocks: W[K][64] fp32 -> Wt[64][K] bf16
        int i = (blockIdx.x - nblk) * 256 + threadIdx.x;
        if (i < 128 * 64) {
            int k = i >> 6, n = i & 63;
            W1t[n * 128 + k] = f2bf(W1[i]);
        }
        int j = i - 128 * 64;
        if (j >= 0 && j < 64 * 64) {
            int k = j >> 6, n = j & 63;
            W2t[n * 64 + k] = f2bf(W2[j]);
        }
        return;
    }
    __shared__ int hist[NBMAX];
    int t = threadIdx.x;
    for (int b = t; b < nb; b += 256) hist[b] = 0;
    __syncthreads();
    int base = blockIdx.x * CH;
#pragma unroll
    for (int j = 0; j < CH / 1024; ++j) {
        int idx = base + j * 1024 + t * 4;
        if (idx + 4 <= E) {
            int4 d = *(const int4*)(dst + idx);
            atomicAdd(&hist[d.x >> BSHIFT], 1);
            atomicAdd(&hist[d.y >> BSHIFT], 1);
            atomicAdd(&hist[d.z >> BSHIFT], 1);
            atomicAdd(&hist[d.w >> BSHIFT], 1);
        } else {
            for (int k = 0; k < 4; ++k)
                if (idx + k < E) atomicAdd(&hist[dst[idx + k] >> BSHIFT], 1);
        }
    }
    __syncthreads();
    for (int b = t; b < nb; b += 256) histmat[blockIdx.x * nb + b] = hist[b];
}

// ---------------- pass B1: per-bucket scan over blocks (nblk <= 1024) -------
__global__ __launch_bounds__(256) void scancol_kernel(const int* __restrict__ histmat,
                                                      int* __restrict__ colbase,
                                                      int* __restrict__ buckettotal,
                                                      int nb, int nblk) {
    __shared__ int ts[256];
    int b = blockIdx.x;
    int t = threadIdx.x;
    int v[4];
    int tsum = 0;
#pragma unroll
    for (int k = 0; k < 4; ++k) {
        int blk = t * 4 + k;
        v[k] = (blk < nblk) ? histmat[blk * nb + b] : 0;
        tsum += v[k];
    }
    ts[t] = tsum;
    __syncthreads();
    for (int ofs = 1; ofs < 256; ofs <<= 1) {
        int val = (t >= ofs) ? ts[t - ofs] : 0;
        __syncthreads();
        ts[t] += val;
        __syncthreads();
    }
    int run = ts[t] - tsum;
#pragma unroll
    for (int k = 0; k < 4; ++k) {
        int blk = t * 4 + k;
        if (blk < nblk) colbase[blk * nb + b] = run;
        run += v[k];
    }
    if (t == 255) buckettotal[b] = ts[255];
}

// ---------------- pass B2: scan bucket totals (single block) ----------------
__global__ __launch_bounds__(256) void scanbucket_kernel(const int* __restrict__ buckettotal,
                                                         int* __restrict__ bucketbase,
                                                         int nb, int E) {
    __shared__ int ts[256];
    int t = threadIdx.x;
    int v[4];
    int tsum = 0;
#pragma unroll
    for (int k = 0; k < 4; ++k) {
        int b = t * 4 + k;
        v[k] = (b < nb) ? buckettotal[b] : 0;
        tsum += v[k];
    }
    ts[t] = tsum;
    __syncthreads();
    for (int ofs = 1; ofs < 256; ofs <<= 1) {
        int val = (t >= ofs) ? ts[t - ofs] : 0;
        __syncthreads();
        ts[t] += val;
        __syncthreads();
    }
    int run = ts[t] - tsum;
#pragma unroll
    for (int k = 0; k < 4; ++k) {
        int b = t * 4 + k;
        if (b < nb) bucketbase[b] = run;
        run += v[k];
    }
    if (t == 0) bucketbase[nb] = E;
}

// ---------------- pass C: scatter into bucket regions (LDS cursors) ---------
__global__ __launch_bounds__(256) void bscatter_kernel(const int* __restrict__ src,
                                                       const int* __restrict__ dst,
                                                       const int* __restrict__ colbase,
                                                       const int* __restrict__ bucketbase,
                                                       int* __restrict__ packed,
                                                       int E, int nb) {
    __shared__ int cur[NBMAX];
    int t = threadIdx.x;
    for (int b = t; b < nb; b += 256)
        cur[b] = bucketbase[b] + colbase[blockIdx.x * nb + b];
    __syncthreads();
    int base = blockIdx.x * CH;
#pragma unroll
    for (int j = 0; j < CH / 1024; ++j) {
        int idx = base + j * 1024 + t * 4;
        if (idx + 4 <= E) {
            int4 d = *(const int4*)(dst + idx);
            int4 s = *(const int4*)(src + idx);
            int p;
            p = atomicAdd(&cur[d.x >> BSHIFT], 1); packed[p] = ((d.x & 127) << 17) | s.x;
            p = atomicAdd(&cur[d.y >> BSHIFT], 1); packed[p] = ((d.y & 127) << 17) | s.y;
            p = atomicAdd(&cur[d.z >> BSHIFT], 1); packed[p] = ((d.z & 127) << 17) | s.z;
            p = atomicAdd(&cur[d.w >> BSHIFT], 1); packed[p] = ((d.w & 127) << 17) | s.w;
        } else {
            for (int k = 0; k < 4; ++k)
                if (idx + k < E) {
                    int dd = dst[idx + k], ss = src[idx + k];
                    int p = atomicAdd(&cur[dd >> BSHIFT], 1);
                    packed[p] = ((dd & 127) << 17) | ss;
                }
        }
    }
}

// ---------------- pass D: within-bucket CSR + rowptr + dinv (LDS-cached) ----
__global__ __launch_bounds__(256) void bcsr_kernel(const int* __restrict__ packed,
                                                   const int* __restrict__ bucketbase,
                                                   int* __restrict__ rowptr,
                                                   float* __restrict__ dinv,
                                                   int* __restrict__ csr,
                                                   int N, int nb) {
    __shared__ int deg[128];
    __shared__ int lrp[128];
    __shared__ int ts[128];
    __shared__ int ebuf[MAXB];
    __shared__ int obuf[MAXB];
    int b = blockIdx.x;
    int t = threadIdx.x;
    if (t < 128) deg[t] = 0;
    __syncthreads();
    int bb0 = bucketbase[b];
    int bb1 = bucketbase[b + 1];
    int cnt = bb1 - bb0;
    bool fits = (cnt <= MAXB);
    if (fits) {
        for (int i = t; i < cnt; i += 256) {
            int v = packed[bb0 + i];
            ebuf[i] = v;
            atomicAdd(&deg[v >> 17], 1);
        }
    } else {
        for (int i = t; i < cnt; i += 256)
            atomicAdd(&deg[packed[bb0 + i] >> 17], 1);
    }
    __syncthreads();
    if (t < 128) ts[t] = deg[t];
    __syncthreads();
    for (int ofs = 1; ofs < 128; ofs <<= 1) {
        int v = (t < 128 && t >= ofs) ? ts[t - ofs] : 0;
        __syncthreads();
        if (t < 128) ts[t] += v;
        __syncthreads();
    }
    int node0 = b << BSHIFT;
    int nlocal = min(128, N - node0);
    if (t < 128) lrp[t] = ts[t] - deg[t];
    if (t < nlocal) {
        rowptr[node0 + t] = bb0 + (ts[t] - deg[t]);
        dinv[node0 + t] = rsqrtf((float)(deg[t] + 1));
    }
    if (t == nlocal) rowptr[node0 + nlocal] = bb1;
    __syncthreads();
    if (fits) {
        for (int i = t; i < cnt; i += 256) {
            int v = ebuf[i];
            int p = atomicAdd(&lrp[v >> 17], 1);
            obuf[p] = v & 0x1FFFF;
        }
        __syncthreads();
        for (int i = t; i < cnt; i += 256) csr[bb0 + i] = obuf[i];  // coalesced
    } else {
        for (int i = t; i < cnt; i += 256) {
            int v = packed[bb0 + i];
            int p = atomicAdd(&lrp[v >> 17], 1);
            csr[bb0 + p] = v & 0x1FFFF;
        }
    }
}

// ------- MFMA GEMM: Ybf[M,64](bf16) = (X[M,K] @ W[K,64]) * dinv[row] -------
template <int K, bool XBF16>
__global__ __launch_bounds__(256) void gemm_mfma(const void* __restrict__ Xv,
                                                 const unsigned short* __restrict__ Wt,
                                                 const float* __restrict__ dinv,
                                                 unsigned short* __restrict__ Ybf, int M) {
    constexpr int KP = K + 8;
    __shared__ unsigned short Xs[64 * KP];   // reused as Cs (64*72) in epilogue
    __shared__ unsigned short Ws[64 * KP];
    int t = threadIdx.x;
    int row0 = blockIdx.x * 64;

    for (int i = t; i < 64 * K / 8; i += 256) {
        int r = i / (K / 8), c8 = i % (K / 8);
        *(uint4*)(&Ws[r * KP + c8 * 8]) = ((const uint4*)Wt)[i];
    }
    if (XBF16) {
        const unsigned short* X = (const unsigned short*)Xv;
        for (int i = t; i < 64 * K / 8; i += 256) {
            int r = i / (K / 8), c8 = i % (K / 8);
            int gr = row0 + r;
            uint4 v = make_uint4(0u, 0u, 0u, 0u);
            if (gr < M) v = ((const uint4*)(X + (size_t)gr * K))[c8];
            *(uint4*)(&Xs[r * KP + c8 * 8]) = v;
        }
    } else {
        const float* X = (const float*)Xv;
        for (int i = t; i < 64 * K / 4; i += 256) {
            int r = i / (K / 4), c4 = i % (K / 4);
            int gr = row0 + r;
            float4 v = make_float4(0.f, 0.f, 0.f, 0.f);
            if (gr < M) v = ((const float4*)(X + (size_t)gr * K))[c4];
            uint2 p;
            p.x = pack2(v.x, v.y);
            p.y = pack2(v.z, v.w);
            *(uint2*)(&Xs[r * KP + c4 * 4]) = p;
        }
    }
    __syncthreads();

    int lane = t & 63;
    int w = t >> 6;
    int m = lane & 15;
    int q = lane >> 4;

    f32x4 acc[4];
#pragma unroll
    for (int nt = 0; nt < 4; ++nt) acc[nt] = (f32x4){0.f, 0.f, 0.f, 0.f};

#pragma unroll
    for (int s = 0; s < K / 32; ++s) {
        bf16x8 a = *(const bf16x8*)(&Xs[(16 * w + m) * KP + s * 32 + q * 8]);
#pragma unroll
        for (int nt = 0; nt < 4; ++nt) {
            bf16x8 b = *(const bf16x8*)(&Ws[(16 * nt + m) * KP + s * 32 + q * 8]);
            acc[nt] = __builtin_amdgcn_mfma_f32_16x16x32_bf16(a, b, acc[nt], 0, 0, 0);
        }
    }
    __syncthreads();

    unsigned short* Cs = Xs;
#pragma unroll
    for (int nt = 0; nt < 4; ++nt)
#pragma unroll
        for (int r = 0; r < 4; ++r) {
            int row = 16 * w + q * 4 + r;
            int gr = row0 + row;
            float d = (gr < M) ? dinv[gr] : 0.f;
            Cs[row * 72 + nt * 16 + m] = f2bf(acc[nt][r] * d);
        }
    __syncthreads();
    for (int i = t; i < 64 * 64 / 8; i += 256) {
        int r = i >> 3, c8 = i & 7;
        int gr = row0 + r;
        if (gr < M)
            *(uint4*)(Ybf + (size_t)gr * 64 + c8 * 8) = *(const uint4*)(&Cs[r * 72 + c8 * 8]);
    }
}

// ---------------- pull aggregation + epilogue ----------------
__global__ __launch_bounds__(256) void aggregate_kernel(const unsigned* __restrict__ hsu,
                                                        const int* __restrict__ rowptr,
                                                        const int* __restrict__ csr,
                                                        const float* __restrict__ dinv,
                                                        const float* __restrict__ bias,
                                                        void* __restrict__ outv, int N,
                                                        int do_relu, int obf) {
    int t = threadIdx.x;
    int node = blockIdx.x * 32 + (t >> 3);
    if (node >= N) return;
    int sub = t & 7;
    int gbase = t & 56;

    float acc[8];
    {
        uint4 v = *(const uint4*)(hsu + (size_t)node * 32 + sub * 4);  // self-loop
        acc[0] = blo(v.x); acc[1] = bhi(v.x);
        acc[2] = blo(v.y); acc[3] = bhi(v.y);
        acc[4] = blo(v.z); acc[5] = bhi(v.z);
        acc[6] = blo(v.w); acc[7] = bhi(v.w);
    }
    int e0 = rowptr[node];
    int e1 = rowptr[node + 1];

    int e = e0;
    for (; e + 8 <= e1; e += 8) {
        int idx = csr[e + sub];
#pragma unroll
        for (int j = 0; j < 8; ++j) {
            int s = __shfl(idx, gbase + j, 64);
            uint4 v = *(const uint4*)(hsu + (size_t)s * 32 + sub * 4);
            acc[0] += blo(v.x); acc[1] += bhi(v.x);
            acc[2] += blo(v.y); acc[3] += bhi(v.y);
            acc[4] += blo(v.z); acc[5] += bhi(v.z);
            acc[6] += blo(v.w); acc[7] += bhi(v.w);
        }
    }
    for (; e < e1; ++e) {
        int s = csr[e];
        uint4 v = *(const uint4*)(hsu + (size_t)s * 32 + sub * 4);
        acc[0] += blo(v.x); acc[1] += bhi(v.x);
        acc[2] += blo(v.y); acc[3] += bhi(v.y);
        acc[4] += blo(v.z); acc[5] += bhi(v.z);
        acc[6] += blo(v.w); acc[7] += bhi(v.w);
    }

    float d = dinv[node];
    float4 b0 = *(const float4*)(bias + sub * 8);
    float4 b1 = *(const float4*)(bias + sub * 8 + 4);
    float o[8];
    o[0] = fmaf(acc[0], d, b0.x); o[1] = fmaf(acc[1], d, b0.y);
    o[2] = fmaf(acc[2], d, b0.z); o[3] = fmaf(acc[3], d, b0.w);
    o[4] = fmaf(acc[4], d, b1.x); o[5] = fmaf(acc[5], d, b1.y);
    o[6] = fmaf(acc[6], d, b1.z); o[7] = fmaf(acc[7], d, b1.w);
    if (do_relu) {
#pragma unroll
        for (int k = 0; k < 8; ++k) o[k] = fmaxf(o[k], 0.f);
    }
    if (obf) {
        unsigned short* outb = (unsigned short*)outv;
        uint4 p;
        p.x = pack2(o[0], o[1]); p.y = pack2(o[2], o[3]);
        p.z = pack2(o[4], o[5]); p.w = pack2(o[6], o[7]);
        *(uint4*)(outb + (size_t)node * 64 + sub * 8) = p;
    } else {
        float* op = (float*)outv + (size_t)node * 64 + sub * 8;
        *(float4*)(op)     = make_float4(o[0], o[1], o[2], o[3]);
        *(float4*)(op + 4) = make_float4(o[4], o[5], o[6], o[7]);
    }
}

// ---------------- launch ----------------
extern "C" void kernel_launch(void* const* d_in, const int* in_sizes, int n_in,
                              void* d_out, int out_size, void* d_ws, size_t ws_size,
                              hipStream_t stream) {
    const float* x  = (const float*)d_in[0];
    const int*   ei = (const int*)d_in[1];   // [2, E] int32
    const float* W1 = (const float*)d_in[2];
    const float* b1 = (const float*)d_in[3];
    const float* W2 = (const float*)d_in[4];
    const float* b2 = (const float*)d_in[5];

    const int N = in_sizes[0] / 128;  // 100000
    const int E = in_sizes[1] / 2;    // 3200000
    const int* src = ei;
    const int* dst = ei + E;
    float* out = (float*)d_out;

    const int nb   = (N + 127) >> BSHIFT;  // 782
    const int nblk = (E + CH - 1) / CH;    // 782

    char* ws = (char*)d_ws;
    size_t off = 0;
    auto alloc = [&](size_t bytes) -> char* {
        char* p = ws + off;
        off = (off + bytes + 255) & ~(size_t)255;
        return p;
    };
    // persistent
    int*   csr         = (int*)alloc((size_t)E * 4);
    int*   rowptr      = (int*)alloc((size_t)(N + 1) * 4);
    float* dinv        = (float*)alloc((size_t)N * 4);
    int*   bucketbase  = (int*)alloc((size_t)(nb + 1) * 4);
    int*   buckettotal = (int*)alloc((size_t)nb * 4);
    unsigned short* W1t = (unsigned short*)alloc(64 * 128 * 2);
    unsigned short* W2t = (unsigned short*)alloc(64 * 64 * 2);
    unsigned short* bufA = (unsigned short*)alloc((size_t)N * 64 * 2);  // bf16 h*dinv
    unsigned short* bufB = (unsigned short*)alloc((size_t)N * 64 * 2);  // bf16 relu(agg1)
    // transient (dead before gemm1 writes bufA) — alias bufA+bufB region
    // histmat: nblk*nb*4 = 782*782*4 ~ 2.45 MB; packed: E*4 = 12.8 MB
    int* histmat = (int*)bufA;
    int* packed  = (int*)((char*)bufA + ((size_t)nblk * nb * 4 + 255 & ~(size_t)255) + 256);

    hist_kernel<<<nblk + 48, 256, 0, stream>>>(dst, histmat, E, nb, nblk, W1, W2, W1t, W2t);
    scancol_kernel<<<nb, 256, 0, stream>>>(histmat, histmat, buckettotal, nb, nblk);
    scanbucket_kernel<<<1, 256, 0, stream>>>(buckettotal, bucketbase, nb, E);
    bscatter_kernel<<<nblk, 256, 0, stream>>>(src, dst, histmat, bucketbase, packed, E, nb);
    bcsr_kernel<<<nb, 256, 0, stream>>>(packed, bucketbase, rowptr, dinv, csr, N, nb);

    gemm_mfma<128, false><<<(N + 63) / 64, 256, 0, stream>>>(x, W1t, dinv, bufA, N);
    aggregate_kernel<<<(N + 31) / 32, 256, 0, stream>>>((const unsigned*)bufA, rowptr, csr,
                                                        dinv, b1, bufB, N, 1, 1);
    gemm_mfma<64, true><<<(N + 63) / 64, 256, 0, stream>>>(bufB, W2t, dinv, bufA, N);
    aggregate_kernel<<<(N + 31) / 32, 256, 0, stream>>>((const unsigned*)bufA, rowptr, csr,
                                                        dinv, b2, out, N, 0, 0);
}